// Round 2
// baseline (310.057 us; speedup 1.0000x reference)
//
#include <hip/hip_runtime.h>

#define SAMPLES_PER_BLOCK 128
#define THREADS 128
#define CHUNK_FLOATS 27                 // per-sample floats per middle-group chunk
#define STAGE_THREADS 108               // 108 = 4 * 27; each owns fixed (s0, j0)
#define STAGE_ITERS 32                  // 108 * 32 = 3456 = 128 * 27

__device__ __forceinline__ float fast_sigmoid(float v) {
    float e = __expf(-v);
    return __builtin_amdgcn_rcpf(1.0f + e);
}

__global__ __launch_bounds__(THREADS, 6) void olcnn_kernel(
    const float* __restrict__ x,
    const float* __restrict__ Wc, const float* __restrict__ bc,
    const float* __restrict__ Wh, const float* __restrict__ bh,
    const float* __restrict__ Wm, const float* __restrict__ bm,
    const float* __restrict__ Wo, const float* __restrict__ bo,
    float* __restrict__ out)
{
    // 128 samples * 27 floats = 13824 B LDS -> 11 blocks/CU by LDS (was 3).
    // Stride 27 (odd) => only 2-way bank aliasing across 64 lanes (free).
    __shared__ float sx[SAMPLES_PER_BLOCK * CHUNK_FLOATS];
    const int tid = threadIdx.x;
    const long long sampleBase = (long long)blockIdx.x * SAMPLES_PER_BLOCK;
    const float* xblk = x + sampleBase * 81;

    // Fixed staging slot: thread t owns sample s0 + 4i, float j0 of each chunk.
    const int s0 = tid / 27;            // valid for tid < 108
    const int j0 = tid - s0 * 27;

    float res[4];

    #pragma unroll
    for (int G = 0; G < 3; ++G) {
        if (G) __syncthreads();         // all reads of previous chunk done
        if (tid < STAGE_THREADS) {
            const float* src = xblk + 81 * s0 + 27 * G + j0;
            float* dst = &sx[27 * s0 + j0];
            #pragma unroll
            for (int i = 0; i < STAGE_ITERS; ++i)
                dst[i * (4 * 27)] = src[i * (4 * 81)];   // coalesced 27-dword runs
        }
        __syncthreads();

        const float* px = &sx[tid * CHUNK_FLOATS];  // chunk-local: pr*9 + gc*3 + pc

        // hidden outputs of patches g = 3G + j, j = 0..2
        float hbuf[9];
        #pragma unroll
        for (int j = 0; j < 3; ++j) {
            const int g = G * 3 + j;    // gr = G, gc = j
            float pix[9];
            #pragma unroll
            for (int pr = 0; pr < 3; ++pr)
                #pragma unroll
                for (int pc = 0; pc < 3; ++pc)
                    pix[pr * 3 + pc] = px[pr * 9 + j * 3 + pc];

            float feat[9];
            #pragma unroll
            for (int k = 0; k < 9; ++k) {
                float acc = bc[g * 9 + k];
                #pragma unroll
                for (int p = 0; p < 9; ++p)
                    acc = fmaf(pix[p], Wc[(g * 9 + k) * 9 + p], acc);
                feat[k] = fast_sigmoid(acc);
            }
            #pragma unroll
            for (int n = 0; n < 3; ++n) {
                float acc = bh[g * 3 + n];
                #pragma unroll
                for (int p = 0; p < 9; ++p)
                    acc = fmaf(feat[p], Wh[(g * 3 + n) * 9 + p], acc);
                hbuf[j * 3 + n] = fast_sigmoid(acc);
            }
        }

        // middle group G
        float m[4];
        #pragma unroll
        for (int n = 0; n < 4; ++n) {
            float acc = bm[G * 4 + n];
            #pragma unroll
            for (int p = 0; p < 9; ++p)
                acc = fmaf(hbuf[p], Wm[(G * 4 + n) * 9 + p], acc);
            m[n] = fast_sigmoid(acc);
        }

        // fold into outputs that read group G (c % 3 == G): c = G, and c = 3 for G = 0
        {
            float acc = bo[G];
            #pragma unroll
            for (int p = 0; p < 4; ++p)
                acc = fmaf(m[p], Wo[G * 4 + p], acc);
            res[G] = acc;
        }
        if (G == 0) {
            float acc = bo[3];
            #pragma unroll
            for (int p = 0; p < 4; ++p)
                acc = fmaf(m[p], Wo[3 * 4 + p], acc);
            res[3] = acc;
        }
    }

    float4 o;
    o.x = res[0]; o.y = res[1]; o.z = res[2]; o.w = res[3];
    ((float4*)out)[sampleBase + tid] = o;   // coalesced 16B/lane store
}

extern "C" void kernel_launch(void* const* d_in, const int* in_sizes, int n_in,
                              void* d_out, int out_size, void* d_ws, size_t ws_size,
                              hipStream_t stream) {
    const float* x  = (const float*)d_in[0];
    const float* Wc = (const float*)d_in[1];
    const float* bc = (const float*)d_in[2];
    const float* Wh = (const float*)d_in[3];
    const float* bh = (const float*)d_in[4];
    const float* Wm = (const float*)d_in[5];
    const float* bm = (const float*)d_in[6];
    const float* Wo = (const float*)d_in[7];
    const float* bo = (const float*)d_in[8];
    float* out = (float*)d_out;

    const int B = in_sizes[0] / 81;                  // 524288
    const int blocks = B / SAMPLES_PER_BLOCK;        // 4096 (exact)
    olcnn_kernel<<<blocks, THREADS, 0, stream>>>(x, Wc, bc, Wh, bh, Wm, bm,
                                                 Wo, bo, out);
}

// Round 3
// 276.511 us; speedup vs baseline: 1.1213x; 1.1213x over previous
//
#include <hip/hip_runtime.h>
#include <hip/hip_fp16.h>

#define THREADS 64            // ONE wave per block: barrier is trivially satisfied,
                              // blocks/waves fully decoupled -> staggered staging
#define SAMPLES_PER_BLOCK 64

__device__ __forceinline__ float fast_sigmoid(float v) {
    float e = __expf(-v);
    return __builtin_amdgcn_rcpf(1.0f + e);
}

__global__ __launch_bounds__(THREADS) void olcnn_kernel(
    const float* __restrict__ x,
    const float* __restrict__ Wc, const float* __restrict__ bc,
    const float* __restrict__ Wh, const float* __restrict__ bh,
    const float* __restrict__ Wm, const float* __restrict__ bm,
    const float* __restrict__ Wo, const float* __restrict__ bo,
    float* __restrict__ out)
{
    // 64 samples * 81 halfs = 10368 B -> 15 blocks/CU by LDS (was 3 @ fp32/128).
    // Half-stride 81/sample: compute-phase reads land exactly 2 lanes/bank (free).
    __shared__ __align__(16) __half sh[SAMPLES_PER_BLOCK * 81];
    const int tid = threadIdx.x;
    const long long sampleBase = (long long)blockIdx.x * SAMPLES_PER_BLOCK;

    // --- Stage: contiguous 64*81 floats, coalesced float4, cvt -> fp16 in LDS.
    // 64*81 = 5184 dwords = 1296 float4 = 20*64 + 16.
    const float4* xv = (const float4*)(x + sampleBase * 81);
    uint2* sv = (uint2*)sh;               // one uint2 = 4 packed halfs
    #pragma unroll
    for (int i = 0; i < 20; ++i) {
        float4 v = xv[tid + i * THREADS];
        union { uint2 u; __half2 h[2]; } pk;
        pk.h[0] = __floats2half2_rn(v.x, v.y);
        pk.h[1] = __floats2half2_rn(v.z, v.w);
        sv[tid + i * THREADS] = pk.u;
    }
    if (tid < 16) {
        float4 v = xv[tid + 20 * THREADS];
        union { uint2 u; __half2 h[2]; } pk;
        pk.h[0] = __floats2half2_rn(v.x, v.y);
        pk.h[1] = __floats2half2_rn(v.z, v.w);
        sv[tid + 20 * THREADS] = pk.u;
    }
    __syncthreads();   // single-wave workgroup: no cross-wave coupling

    const __half* px = &sh[tid * 81];   // x offset: gr*27 + pr*9 + gc*3 + pc

    // Fused per middle-group G: conv patches (G,0..2) -> hidden -> middle -> out
    float res[4];
    #pragma unroll
    for (int G = 0; G < 3; ++G) {
        float hbuf[9];
        #pragma unroll
        for (int j = 0; j < 3; ++j) {
            const int g = G * 3 + j;      // gr = G, gc = j
            float pix[9];
            #pragma unroll
            for (int pr = 0; pr < 3; ++pr)
                #pragma unroll
                for (int pc = 0; pc < 3; ++pc)
                    pix[pr * 3 + pc] = __half2float(px[G * 27 + pr * 9 + j * 3 + pc]);

            float feat[9];
            #pragma unroll
            for (int k = 0; k < 9; ++k) {
                float acc = bc[g * 9 + k];
                #pragma unroll
                for (int p = 0; p < 9; ++p)
                    acc = fmaf(pix[p], Wc[(g * 9 + k) * 9 + p], acc);
                feat[k] = fast_sigmoid(acc);
            }
            #pragma unroll
            for (int n = 0; n < 3; ++n) {
                float acc = bh[g * 3 + n];
                #pragma unroll
                for (int p = 0; p < 9; ++p)
                    acc = fmaf(feat[p], Wh[(g * 3 + n) * 9 + p], acc);
                hbuf[j * 3 + n] = fast_sigmoid(acc);
            }
        }

        float m[4];
        #pragma unroll
        for (int n = 0; n < 4; ++n) {
            float acc = bm[G * 4 + n];
            #pragma unroll
            for (int p = 0; p < 9; ++p)
                acc = fmaf(hbuf[p], Wm[(G * 4 + n) * 9 + p], acc);
            m[n] = fast_sigmoid(acc);
        }

        // outputs reading group G (c % 3 == G): c = G, plus c = 3 for G = 0
        {
            float acc = bo[G];
            #pragma unroll
            for (int p = 0; p < 4; ++p)
                acc = fmaf(m[p], Wo[G * 4 + p], acc);
            res[G] = acc;
        }
        if (G == 0) {
            float acc = bo[3];
            #pragma unroll
            for (int p = 0; p < 4; ++p)
                acc = fmaf(m[p], Wo[3 * 4 + p], acc);
            res[3] = acc;
        }
    }

    float4 o;
    o.x = res[0]; o.y = res[1]; o.z = res[2]; o.w = res[3];
    ((float4*)out)[sampleBase + tid] = o;   // coalesced 16B/lane store
}

extern "C" void kernel_launch(void* const* d_in, const int* in_sizes, int n_in,
                              void* d_out, int out_size, void* d_ws, size_t ws_size,
                              hipStream_t stream) {
    const float* x  = (const float*)d_in[0];
    const float* Wc = (const float*)d_in[1];
    const float* bc = (const float*)d_in[2];
    const float* Wh = (const float*)d_in[3];
    const float* bh = (const float*)d_in[4];
    const float* Wm = (const float*)d_in[5];
    const float* bm = (const float*)d_in[6];
    const float* Wo = (const float*)d_in[7];
    const float* bo = (const float*)d_in[8];
    float* out = (float*)d_out;

    const int B = in_sizes[0] / 81;                   // 524288
    const int blocks = B / SAMPLES_PER_BLOCK;         // 8192 (exact)
    olcnn_kernel<<<blocks, THREADS, 0, stream>>>(x, Wc, bc, Wh, bh, Wm, bm,
                                                 Wo, bo, out);
}